// Round 3
// baseline (390.571 us; speedup 1.0000x reference)
//
#include <hip/hip_runtime.h>
#include <math.h>

#define NN 102400
#define D 256
#define B 2048

typedef __bf16 bf16x8 __attribute__((ext_vector_type(8)));
typedef float f32x4 __attribute__((ext_vector_type(4)));

// K0: seg_start[b] = lower_bound(seg_ids, b); seg_start[B] = NN
__global__ void k_bounds(const int* __restrict__ seg, int* __restrict__ seg_start) {
    int b = blockIdx.x * blockDim.x + threadIdx.x;
    if (b > B) return;
    int lo = 0, hi = NN;
    while (lo < hi) { int mid = (lo + hi) >> 1; if (seg[mid] < b) lo = mid + 1; else hi = mid; }
    seg_start[b] = lo;
}

// K1: anchor (segment mean) -> out[:, 256:512]
__global__ void k_anchor(const float* __restrict__ ifeat, const int* __restrict__ seg_start,
                         float* __restrict__ out) {
    int b = blockIdx.x;
    int t = threadIdx.x; // 256 threads, thread = column
    int s = seg_start[b], e = seg_start[b + 1];
    float a0 = 0.f, a1 = 0.f, a2 = 0.f, a3 = 0.f;
    int i = s;
    for (; i + 4 <= e; i += 4) {
        a0 += ifeat[(size_t)(i + 0) * D + t];
        a1 += ifeat[(size_t)(i + 1) * D + t];
        a2 += ifeat[(size_t)(i + 2) * D + t];
        a3 += ifeat[(size_t)(i + 3) * D + t];
    }
    for (; i < e; ++i) a0 += ifeat[(size_t)i * D + t];
    float sum = (a0 + a1) + (a2 + a3);
    int cnt = e - s;
    float inv = 1.0f / (float)(cnt > 0 ? cnt : 1);
    out[(size_t)b * 512 + 256 + t] = sum * inv;
}

// K2: feat_v = anchor @ Wv^T + bv, 16 segments per block
__global__ void k_featv(const float* __restrict__ out, const float* __restrict__ Wv,
                        const float* __restrict__ bv, float* __restrict__ feat_v) {
    __shared__ float anc[16][D];
    int b0 = blockIdx.x * 16;
    int t = threadIdx.x; // 256, thread = output column j
#pragma unroll
    for (int r = 0; r < 16; ++r) anc[r][t] = out[(size_t)(b0 + r) * 512 + 256 + t];
    __syncthreads();
    float acc[16];
#pragma unroll
    for (int s = 0; s < 16; ++s) acc[s] = 0.f;
    const float* wrow = Wv + (size_t)t * D;
    for (int k = 0; k < D; k += 4) {
        float4 w = *(const float4*)(wrow + k);
#pragma unroll
        for (int s = 0; s < 16; ++s) {
            acc[s] += anc[s][k] * w.x + anc[s][k + 1] * w.y
                    + anc[s][k + 2] * w.z + anc[s][k + 3] * w.w;
        }
    }
    float bj = bv[t];
#pragma unroll
    for (int s = 0; s < 16; ++s) feat_v[(size_t)(b0 + s) * D + t] = acc[s] + bj;
}

// K3 (MFMA, Wu-resident): e[n] = we . sigmoid(bf16(ifeat[n]) @ bf16(Wu)^T + feat_v[seg[n]])
// 256 blocks x 512 thr (8 waves). Wu staged ONCE into 128 KB LDS (bf16, XOR-swizzled).
// Then barrier-free: each wave grid-strides 3200 items of (32 nodes x 256 cols),
// A-fragments direct from global (fp32 -> bf16 in reg, 1-chunk prefetch pipeline).
__global__ __launch_bounds__(512, 2)
void k_attn_e_mfma(const float* __restrict__ ifeat, const float* __restrict__ Wu,
                   const float* __restrict__ feat_v, const float* __restrict__ we,
                   const int* __restrict__ seg_ids, float* __restrict__ e_out) {
    __shared__ __bf16 Bs[256 * 256];   // [j][k] bf16, byte addr = j*512 + (k*2 ^ ((j&7)<<4))

    int tx = threadIdx.x;
    int lane = tx & 63;
    int w = tx >> 6;
    int ln15 = lane & 15;
    int lg = lane >> 4;

    // ---- stage Wu once: thread -> (row j = tx>>1, k-half h = tx&1), 128 elems each ----
    {
        int j = tx >> 1, h = tx & 1;
        const float* wp = Wu + (size_t)j * D + h * 128;
        char* rowp = (char*)Bs + j * 512;
        int sw = (j & 7) << 4;
#pragma unroll
        for (int q = 0; q < 16; ++q) {
            float4 b0 = *(const float4*)(wp + q * 8);
            float4 b1 = *(const float4*)(wp + q * 8 + 4);
            bf16x8 v;
            v[0] = (__bf16)b0.x; v[1] = (__bf16)b0.y; v[2] = (__bf16)b0.z; v[3] = (__bf16)b0.w;
            v[4] = (__bf16)b1.x; v[5] = (__bf16)b1.y; v[6] = (__bf16)b1.z; v[7] = (__bf16)b1.w;
            *(bf16x8*)(rowp + ((h * 256 + q * 16) ^ sw)) = v;
        }
    }
    __syncthreads();

    int wave_gid = blockIdx.x * 8 + w;
    int swr = (ln15 & 7) << 4;   // read-side swizzle (j&7 == ln15&7 for our frag rows)

    for (int item = wave_gid; item < NN / 32; item += 2048) {
        int nb = item * 32;

        f32x4 acc[2][16];
#pragma unroll
        for (int rt = 0; rt < 2; ++rt)
#pragma unroll
            for (int ct = 0; ct < 16; ++ct) acc[rt][ct] = (f32x4){0.f, 0.f, 0.f, 0.f};

        const float* ap0 = ifeat + (size_t)(nb + ln15) * D + lg * 8;
        const float* ap1 = ap0 + (size_t)16 * D;

        float4 pa[2][2][2];  // [buf][rt][16B-half] — all indices static (full unroll)
        pa[0][0][0] = *(const float4*)(ap0);
        pa[0][0][1] = *(const float4*)(ap0 + 4);
        pa[0][1][0] = *(const float4*)(ap1);
        pa[0][1][1] = *(const float4*)(ap1 + 4);

#pragma unroll
        for (int chunk = 0; chunk < 8; ++chunk) {
            if (chunk < 7) {
                int ko = (chunk + 1) * 32;
                pa[(chunk + 1) & 1][0][0] = *(const float4*)(ap0 + ko);
                pa[(chunk + 1) & 1][0][1] = *(const float4*)(ap0 + ko + 4);
                pa[(chunk + 1) & 1][1][0] = *(const float4*)(ap1 + ko);
                pa[(chunk + 1) & 1][1][1] = *(const float4*)(ap1 + ko + 4);
            }
            bf16x8 af[2];
#pragma unroll
            for (int rt = 0; rt < 2; ++rt) {
                float4 x = pa[chunk & 1][rt][0];
                float4 y = pa[chunk & 1][rt][1];
                af[rt][0] = (__bf16)x.x; af[rt][1] = (__bf16)x.y;
                af[rt][2] = (__bf16)x.z; af[rt][3] = (__bf16)x.w;
                af[rt][4] = (__bf16)y.x; af[rt][5] = (__bf16)y.y;
                af[rt][6] = (__bf16)y.z; af[rt][7] = (__bf16)y.w;
            }
            int kbase = chunk * 64 + lg * 16;
#pragma unroll
            for (int ct = 0; ct < 16; ++ct) {
                const char* bp = (const char*)Bs + (ct * 16 + ln15) * 512 + (kbase ^ swr);
                bf16x8 bfv = *(const bf16x8*)bp;
                acc[0][ct] = __builtin_amdgcn_mfma_f32_16x16x32_bf16(af[0], bfv, acc[0][ct], 0, 0, 0);
                acc[1][ct] = __builtin_amdgcn_mfma_f32_16x16x32_bf16(af[1], bfv, acc[1][ct], 0, 0, 0);
            }
        }

        // ---- epilogue: u += feat_v; p += we*sigmoid(u); in-wave reduce over 16 cols ----
        float part[2][4];
#pragma unroll
        for (int rt = 0; rt < 2; ++rt) {
#pragma unroll
            for (int r = 0; r < 4; ++r) {
                int row = nb + rt * 16 + lg * 4 + r;
                int sg = seg_ids[row];
                const float* fv = feat_v + (size_t)sg * D + ln15;
                float p = 0.f;
#pragma unroll
                for (int ct = 0; ct < 16; ++ct) {
                    float u = acc[rt][ct][r] + fv[ct * 16];
                    p += we[ct * 16 + ln15] / (1.0f + __expf(-u));
                }
                part[rt][r] = p;
            }
        }
#pragma unroll
        for (int off = 8; off >= 1; off >>= 1) {
#pragma unroll
            for (int rt = 0; rt < 2; ++rt)
#pragma unroll
                for (int r = 0; r < 4; ++r)
                    part[rt][r] += __shfl_xor(part[rt][r], off, 64);
        }
        if (ln15 == 0) {
#pragma unroll
            for (int rt = 0; rt < 2; ++rt) {
                float4 o = make_float4(part[rt][0], part[rt][1], part[rt][2], part[rt][3]);
                *(float4*)&e_out[nb + rt * 16 + lg * 4] = o;
            }
        }
    }
}

// K4: segment softmax (max, denom) + alpha-weighted segment sum -> out[:, 0:256]
__global__ void k_softmax_rst(const float* __restrict__ ifeat, const int* __restrict__ seg_start,
                              const float* __restrict__ e, float* __restrict__ out) {
    int b = blockIdx.x;
    int t = threadIdx.x; // 256
    int s = seg_start[b], en = seg_start[b + 1];
    float m = -1e30f;
    for (int i = s + t; i < en; i += 256) m = fmaxf(m, e[i]);
#pragma unroll
    for (int off = 32; off >= 1; off >>= 1) m = fmaxf(m, __shfl_xor(m, off, 64));
    __shared__ float red[4];
    if ((t & 63) == 0) red[t >> 6] = m;
    __syncthreads();
    float mall = fmaxf(fmaxf(red[0], red[1]), fmaxf(red[2], red[3]));
    float dsum = 0.f;
    for (int i = s + t; i < en; i += 256) dsum += __expf(e[i] - mall);
#pragma unroll
    for (int off = 32; off >= 1; off >>= 1) dsum += __shfl_xor(dsum, off, 64);
    __shared__ float red2[4];
    if ((t & 63) == 0) red2[t >> 6] = dsum;
    __syncthreads();
    float denom = red2[0] + red2[1] + red2[2] + red2[3];
    float invd = (en > s) ? 1.0f / denom : 0.f;
    float acc = 0.f;
    for (int i = s; i < en; ++i) {
        float alpha = __expf(e[i] - mall) * invd;
        acc += ifeat[(size_t)i * D + t] * alpha;
    }
    out[(size_t)b * 512 + t] = acc;
}

extern "C" void kernel_launch(void* const* d_in, const int* in_sizes, int n_in,
                              void* d_out, int out_size, void* d_ws, size_t ws_size,
                              hipStream_t stream) {
    const float* ifeat = (const float*)d_in[0];
    const float* Wu    = (const float*)d_in[1];
    const float* Wv    = (const float*)d_in[2];
    const float* bv    = (const float*)d_in[3];
    const float* we    = (const float*)d_in[4];
    const int*   seg   = (const int*)d_in[5];
    float* out = (float*)d_out;

    char* ws = (char*)d_ws;
    int*   seg_start = (int*)ws;                                   // (B+1) ints
    float* feat_v    = (float*)(ws + 16384);                       // B*D floats (2 MB)
    float* e_buf     = (float*)(ws + 16384 + (size_t)B * D * 4);   // NN floats (400 KB)

    k_bounds<<<(B + 1 + 255) / 256, 256, 0, stream>>>(seg, seg_start);
    k_anchor<<<B, 256, 0, stream>>>(ifeat, seg_start, out);
    k_featv<<<B / 16, 256, 0, stream>>>(out, Wv, bv, feat_v);
    k_attn_e_mfma<<<256, 512, 0, stream>>>(ifeat, Wu, feat_v, we, seg, e_buf);
    k_softmax_rst<<<B, 256, 0, stream>>>(ifeat, seg_start, e_buf, out);
}

// Round 4
// 388.567 us; speedup vs baseline: 1.0052x; 1.0052x over previous
//
#include <hip/hip_runtime.h>
#include <math.h>

#define NN 102400
#define D 256
#define B 2048

typedef __bf16 bf16x8 __attribute__((ext_vector_type(8)));
typedef float f32x4 __attribute__((ext_vector_type(4)));

// K0: seg_start[b] = lower_bound(seg_ids, b); seg_start[B] = NN
__global__ void k_bounds(const int* __restrict__ seg, int* __restrict__ seg_start) {
    int b = blockIdx.x * blockDim.x + threadIdx.x;
    if (b > B) return;
    int lo = 0, hi = NN;
    while (lo < hi) { int mid = (lo + hi) >> 1; if (seg[mid] < b) lo = mid + 1; else hi = mid; }
    seg_start[b] = lo;
}

// K1: anchor (segment mean) -> out[:, 256:512]
__global__ void k_anchor(const float* __restrict__ ifeat, const int* __restrict__ seg_start,
                         float* __restrict__ out) {
    int b = blockIdx.x;
    int t = threadIdx.x; // 256 threads, thread = column
    int s = seg_start[b], e = seg_start[b + 1];
    float a0 = 0.f, a1 = 0.f, a2 = 0.f, a3 = 0.f;
    int i = s;
    for (; i + 4 <= e; i += 4) {
        a0 += ifeat[(size_t)(i + 0) * D + t];
        a1 += ifeat[(size_t)(i + 1) * D + t];
        a2 += ifeat[(size_t)(i + 2) * D + t];
        a3 += ifeat[(size_t)(i + 3) * D + t];
    }
    for (; i < e; ++i) a0 += ifeat[(size_t)i * D + t];
    float sum = (a0 + a1) + (a2 + a3);
    int cnt = e - s;
    float inv = 1.0f / (float)(cnt > 0 ? cnt : 1);
    out[(size_t)b * 512 + 256 + t] = sum * inv;
}

// K2: feat_v = anchor @ Wv^T + bv, 16 segments per block
__global__ void k_featv(const float* __restrict__ out, const float* __restrict__ Wv,
                        const float* __restrict__ bv, float* __restrict__ feat_v) {
    __shared__ float anc[16][D];
    int b0 = blockIdx.x * 16;
    int t = threadIdx.x; // 256, thread = output column j
#pragma unroll
    for (int r = 0; r < 16; ++r) anc[r][t] = out[(size_t)(b0 + r) * 512 + 256 + t];
    __syncthreads();
    float acc[16];
#pragma unroll
    for (int s = 0; s < 16; ++s) acc[s] = 0.f;
    const float* wrow = Wv + (size_t)t * D;
    for (int k = 0; k < D; k += 4) {
        float4 w = *(const float4*)(wrow + k);
#pragma unroll
        for (int s = 0; s < 16; ++s) {
            acc[s] += anc[s][k] * w.x + anc[s][k + 1] * w.y
                    + anc[s][k + 2] * w.z + anc[s][k + 3] * w.w;
        }
    }
    float bj = bv[t];
#pragma unroll
    for (int s = 0; s < 16; ++s) feat_v[(size_t)(b0 + s) * D + t] = acc[s] + bj;
}

// K3 (MFMA, Wu-resident): e[n] = we . sigmoid(bf16(ifeat[n]) @ bf16(Wu)^T + feat_v[seg[n]])
// 256 blocks x 512 thr (8 waves, 1 block/CU: 128 KB LDS). Wu staged ONCE (bf16, swizzled).
// Item = 16 rows x 256 cols: acc[16] f32x4 = 64 VGPR — NO SPILL (round-3 lesson).
// A direct from global, fp32->bf16 in reg, 2-deep NAMED-register pipeline (static idx only).
__global__ __launch_bounds__(512, 2)
void k_attn_e_mfma(const float* __restrict__ ifeat, const float* __restrict__ Wu,
                   const float* __restrict__ feat_v, const float* __restrict__ we,
                   const int* __restrict__ seg_ids, float* __restrict__ e_out) {
    __shared__ __bf16 Bs[256 * 256];   // [j][k] bf16, byte addr = j*512 + (k*2 ^ ((j&7)<<4))

    int tx = threadIdx.x;
    int lane = tx & 63;
    int w = tx >> 6;
    int ln15 = lane & 15;
    int lg = lane >> 4;

    // ---- stage Wu once: thread -> (row j = tx>>1, k-half h = tx&1), 128 elems each ----
    {
        int j = tx >> 1, h = tx & 1;
        const float* wp = Wu + (size_t)j * D + h * 128;
        char* rowp = (char*)Bs + j * 512;
        int sw = (j & 7) << 4;
#pragma unroll
        for (int q = 0; q < 16; ++q) {
            float4 b0 = *(const float4*)(wp + q * 8);
            float4 b1 = *(const float4*)(wp + q * 8 + 4);
            bf16x8 v;
            v[0] = (__bf16)b0.x; v[1] = (__bf16)b0.y; v[2] = (__bf16)b0.z; v[3] = (__bf16)b0.w;
            v[4] = (__bf16)b1.x; v[5] = (__bf16)b1.y; v[6] = (__bf16)b1.z; v[7] = (__bf16)b1.w;
            *(bf16x8*)(rowp + ((h * 256 + q * 16) ^ sw)) = v;
        }
    }
    __syncthreads();

    // hoist we[] (constant across items): 16 scalars
    float wev[16];
#pragma unroll
    for (int ct = 0; ct < 16; ++ct) wev[ct] = we[ct * 16 + ln15];

    int wave_gid = blockIdx.x * 8 + w;
    int swr = (ln15 & 7) << 4;   // read-side swizzle (j&7 == ln15&7 for frag rows)

    for (int item = wave_gid; item < NN / 16; item += 2048) {
        int nb = item * 16;

        f32x4 acc[16];
#pragma unroll
        for (int ct = 0; ct < 16; ++ct) acc[ct] = (f32x4){0.f, 0.f, 0.f, 0.f};

        const float* ap = ifeat + (size_t)(nb + ln15) * D + lg * 8;

        float4 aX0, aY0, aX1, aY1;   // named 2-deep pipeline — all-static indexing

#define LOADA0(CH) { aX0 = *(const float4*)(ap + (CH) * 32); aY0 = *(const float4*)(ap + (CH) * 32 + 4); }
#define LOADA1(CH) { aX1 = *(const float4*)(ap + (CH) * 32); aY1 = *(const float4*)(ap + (CH) * 32 + 4); }
#define STEP(SX, SY, CH) { \
    bf16x8 af; \
    af[0] = (__bf16)SX.x; af[1] = (__bf16)SX.y; af[2] = (__bf16)SX.z; af[3] = (__bf16)SX.w; \
    af[4] = (__bf16)SY.x; af[5] = (__bf16)SY.y; af[6] = (__bf16)SY.z; af[7] = (__bf16)SY.w; \
    int kbase = (CH) * 64 + lg * 16; \
    _Pragma("unroll") \
    for (int ct = 0; ct < 16; ++ct) { \
        const char* bp = (const char*)Bs + (ct * 16 + ln15) * 512 + (kbase ^ swr); \
        bf16x8 bfv = *(const bf16x8*)bp; \
        acc[ct] = __builtin_amdgcn_mfma_f32_16x16x32_bf16(af, bfv, acc[ct], 0, 0, 0); \
    } }

        LOADA0(0);
        LOADA1(1); STEP(aX0, aY0, 0);
        LOADA0(2); STEP(aX1, aY1, 1);
        LOADA1(3); STEP(aX0, aY0, 2);
        LOADA0(4); STEP(aX1, aY1, 3);
        LOADA1(5); STEP(aX0, aY0, 4);
        LOADA0(6); STEP(aX1, aY1, 5);
        LOADA1(7); STEP(aX0, aY0, 6);
        STEP(aX1, aY1, 7);
#undef LOADA0
#undef LOADA1
#undef STEP

        // ---- epilogue: u += feat_v; p += we*sigmoid(u); reduce over 16 col-lanes ----
        float part[4];
#pragma unroll
        for (int r = 0; r < 4; ++r) {
            int row = nb + lg * 4 + r;
            int sg = seg_ids[row];
            const float* fv = feat_v + (size_t)sg * D + ln15;
            float p = 0.f;
#pragma unroll
            for (int ct = 0; ct < 16; ++ct) {
                float u = acc[ct][r] + fv[ct * 16];
                p += wev[ct] / (1.0f + __expf(-u));
            }
            part[r] = p;
        }
#pragma unroll
        for (int off = 8; off >= 1; off >>= 1) {
#pragma unroll
            for (int r = 0; r < 4; ++r)
                part[r] += __shfl_xor(part[r], off, 64);
        }
        if (ln15 == 0) {
            float4 o = make_float4(part[0], part[1], part[2], part[3]);
            *(float4*)&e_out[nb + lg * 4] = o;
        }
    }
}

// K4: segment softmax (max, denom) + alpha-weighted segment sum -> out[:, 0:256]
__global__ void k_softmax_rst(const float* __restrict__ ifeat, const int* __restrict__ seg_start,
                              const float* __restrict__ e, float* __restrict__ out) {
    int b = blockIdx.x;
    int t = threadIdx.x; // 256
    int s = seg_start[b], en = seg_start[b + 1];
    float m = -1e30f;
    for (int i = s + t; i < en; i += 256) m = fmaxf(m, e[i]);
#pragma unroll
    for (int off = 32; off >= 1; off >>= 1) m = fmaxf(m, __shfl_xor(m, off, 64));
    __shared__ float red[4];
    if ((t & 63) == 0) red[t >> 6] = m;
    __syncthreads();
    float mall = fmaxf(fmaxf(red[0], red[1]), fmaxf(red[2], red[3]));
    float dsum = 0.f;
    for (int i = s + t; i < en; i += 256) dsum += __expf(e[i] - mall);
#pragma unroll
    for (int off = 32; off >= 1; off >>= 1) dsum += __shfl_xor(dsum, off, 64);
    __shared__ float red2[4];
    if ((t & 63) == 0) red2[t >> 6] = dsum;
    __syncthreads();
    float denom = red2[0] + red2[1] + red2[2] + red2[3];
    float invd = (en > s) ? 1.0f / denom : 0.f;
    float acc = 0.f;
    for (int i = s; i < en; ++i) {
        float alpha = __expf(e[i] - mall) * invd;
        acc += ifeat[(size_t)i * D + t] * alpha;
    }
    out[(size_t)b * 512 + t] = acc;
}

extern "C" void kernel_launch(void* const* d_in, const int* in_sizes, int n_in,
                              void* d_out, int out_size, void* d_ws, size_t ws_size,
                              hipStream_t stream) {
    const float* ifeat = (const float*)d_in[0];
    const float* Wu    = (const float*)d_in[1];
    const float* Wv    = (const float*)d_in[2];
    const float* bv    = (const float*)d_in[3];
    const float* we    = (const float*)d_in[4];
    const int*   seg   = (const int*)d_in[5];
    float* out = (float*)d_out;

    char* ws = (char*)d_ws;
    int*   seg_start = (int*)ws;                                   // (B+1) ints
    float* feat_v    = (float*)(ws + 16384);                       // B*D floats (2 MB)
    float* e_buf     = (float*)(ws + 16384 + (size_t)B * D * 4);   // NN floats (400 KB)

    k_bounds<<<(B + 1 + 255) / 256, 256, 0, stream>>>(seg, seg_start);
    k_anchor<<<B, 256, 0, stream>>>(ifeat, seg_start, out);
    k_featv<<<B / 16, 256, 0, stream>>>(out, Wv, bv, feat_v);
    k_attn_e_mfma<<<256, 512, 0, stream>>>(ifeat, Wu, feat_v, we, seg, e_buf);
    k_softmax_rst<<<B, 256, 0, stream>>>(ifeat, seg_start, e_buf, out);
}